// Round 1
// baseline (2456.496 us; speedup 1.0000x reference)
//
#include <hip/hip_runtime.h>

#define N_NODES 50000
#define N_EDGES 600000
#define DH 128
#define BN_EPS 1e-5f

// ---------------------------------------------------------------------------
// Register-tiled fp32 GEMM: C[M,128] = act(A[M,K] @ W[K,128] + bias)
// BM=64, BN=128 (full width), BK=32. 256 threads, each computes 4x8 outputs.
// ---------------------------------------------------------------------------
template <int K, bool RELU>
__global__ __launch_bounds__(256) void gemm128(const float* __restrict__ A,
                                               const float* __restrict__ W,
                                               const float* __restrict__ bias,
                                               float* __restrict__ C, int M) {
  constexpr int BM = 64;
  constexpr int BK = 32;
  __shared__ __align__(16) float As[BK][BM + 1];  // transposed, padded
  __shared__ __align__(16) float Bs[BK][DH];

  const int tid = threadIdx.x;
  const int tr = tid >> 4;   // 0..15 -> row group (4 rows each)
  const int tc = tid & 15;   // 0..15 -> col group (8 cols each)
  const int m0 = blockIdx.x * BM;

  float acc[4][8];
#pragma unroll
  for (int i = 0; i < 4; ++i)
#pragma unroll
    for (int j = 0; j < 8; ++j) acc[i][j] = 0.f;

  for (int k0 = 0; k0 < K; k0 += BK) {
    // Load A tile (64 x 32), float4 along K, store transposed into As[k][m]
#pragma unroll
    for (int l = 0; l < 2; ++l) {
      int id = tid + l * 256;        // 0..511
      int ar = id >> 3;              // 0..63
      int ac = (id & 7) * 4;         // 0..28
      int row = m0 + ar;
      float4 v = make_float4(0.f, 0.f, 0.f, 0.f);
      if (row < M) v = *(const float4*)(A + (size_t)row * K + k0 + ac);
      As[ac + 0][ar] = v.x;
      As[ac + 1][ar] = v.y;
      As[ac + 2][ar] = v.z;
      As[ac + 3][ar] = v.w;
    }
    // Load W tile (32 x 128), coalesced float4
#pragma unroll
    for (int l = 0; l < 4; ++l) {
      int id = tid + l * 256;        // 0..1023
      int wr = id >> 5;              // 0..31
      int wc = (id & 31) * 4;        // 0..124
      *(float4*)&Bs[wr][wc] = *(const float4*)(W + (size_t)(k0 + wr) * DH + wc);
    }
    __syncthreads();

#pragma unroll
    for (int k = 0; k < BK; ++k) {
      float a0 = As[k][tr * 4 + 0];
      float a1 = As[k][tr * 4 + 1];
      float a2 = As[k][tr * 4 + 2];
      float a3 = As[k][tr * 4 + 3];
      float4 b0 = *(const float4*)&Bs[k][tc * 8];
      float4 b1 = *(const float4*)&Bs[k][tc * 8 + 4];
      acc[0][0] += a0 * b0.x; acc[0][1] += a0 * b0.y; acc[0][2] += a0 * b0.z; acc[0][3] += a0 * b0.w;
      acc[0][4] += a0 * b1.x; acc[0][5] += a0 * b1.y; acc[0][6] += a0 * b1.z; acc[0][7] += a0 * b1.w;
      acc[1][0] += a1 * b0.x; acc[1][1] += a1 * b0.y; acc[1][2] += a1 * b0.z; acc[1][3] += a1 * b0.w;
      acc[1][4] += a1 * b1.x; acc[1][5] += a1 * b1.y; acc[1][6] += a1 * b1.z; acc[1][7] += a1 * b1.w;
      acc[2][0] += a2 * b0.x; acc[2][1] += a2 * b0.y; acc[2][2] += a2 * b0.z; acc[2][3] += a2 * b0.w;
      acc[2][4] += a2 * b1.x; acc[2][5] += a2 * b1.y; acc[2][6] += a2 * b1.z; acc[2][7] += a2 * b1.w;
      acc[3][0] += a3 * b0.x; acc[3][1] += a3 * b0.y; acc[3][2] += a3 * b0.z; acc[3][3] += a3 * b0.w;
      acc[3][4] += a3 * b1.x; acc[3][5] += a3 * b1.y; acc[3][6] += a3 * b1.z; acc[3][7] += a3 * b1.w;
    }
    __syncthreads();
  }

  float4 bia0 = *(const float4*)&bias[tc * 8];
  float4 bia1 = *(const float4*)&bias[tc * 8 + 4];
#pragma unroll
  for (int i = 0; i < 4; ++i) {
    int row = m0 + tr * 4 + i;
    if (row >= M) break;
    float4 c0, c1;
    c0.x = acc[i][0] + bia0.x; c0.y = acc[i][1] + bia0.y;
    c0.z = acc[i][2] + bia0.z; c0.w = acc[i][3] + bia0.w;
    c1.x = acc[i][4] + bia1.x; c1.y = acc[i][5] + bia1.y;
    c1.z = acc[i][6] + bia1.z; c1.w = acc[i][7] + bia1.w;
    if (RELU) {
      c0.x = fmaxf(c0.x, 0.f); c0.y = fmaxf(c0.y, 0.f);
      c0.z = fmaxf(c0.z, 0.f); c0.w = fmaxf(c0.w, 0.f);
      c1.x = fmaxf(c1.x, 0.f); c1.y = fmaxf(c1.y, 0.f);
      c1.z = fmaxf(c1.z, 0.f); c1.w = fmaxf(c1.w, 0.f);
    }
    float* cp = C + (size_t)row * DH + tc * 8;
    *(float4*)cp = c0;
    *(float4*)(cp + 4) = c1;
  }
}

// ---------------------------------------------------------------------------
// Scatter-add: y[dst[e]] += x[src[e]], 32 lanes per edge, 4 dims per lane.
// ---------------------------------------------------------------------------
__global__ __launch_bounds__(256) void scatter_add(const float* __restrict__ x,
                                                   const int* __restrict__ eidx,
                                                   float* __restrict__ y) {
  int gid = blockIdx.x * 256 + threadIdx.x;
  int edge = gid >> 5;
  int lane = gid & 31;
  if (edge >= N_EDGES) return;
  int s = eidx[edge];
  int d = eidx[N_EDGES + edge];
  float4 v = *(const float4*)(x + (size_t)s * DH + lane * 4);
  float* out = y + (size_t)d * DH + lane * 4;
  atomicAdd(out + 0, v.x);
  atomicAdd(out + 1, v.y);
  atomicAdd(out + 2, v.z);
  atomicAdd(out + 3, v.w);
}

// ---------------------------------------------------------------------------
// Tail: z[i] = dot(x[i,:], tail_W) + tail_b, plus BN batch-stat partials.
// 32 lanes per node (4 dims each), shuffle reduce, block reduce, 2 atomics.
// ---------------------------------------------------------------------------
__global__ __launch_bounds__(256) void tail_bn1(const float* __restrict__ x,
                                                const float* __restrict__ tw,
                                                const float* __restrict__ tb,
                                                float* __restrict__ z,
                                                float* __restrict__ red) {
  const int lane = threadIdx.x & 31;
  const int grp = threadIdx.x >> 5;  // 0..7
  float4 w = *(const float4*)(tw + lane * 4);
  float accS = 0.f, accQ = 0.f;
  for (int node = blockIdx.x * 8 + grp; node < N_NODES; node += gridDim.x * 8) {
    float4 v = *(const float4*)(x + (size_t)node * DH + lane * 4);
    float p = v.x * w.x + v.y * w.y + v.z * w.z + v.w * w.w;
#pragma unroll
    for (int m = 16; m; m >>= 1) p += __shfl_xor(p, m, 32);
    if (lane == 0) {
      float zv = p + tb[0];
      z[node] = zv;
      accS += zv;
      accQ += zv * zv;
    }
  }
  __shared__ float sS[256];
  __shared__ float sQ[256];
  sS[threadIdx.x] = accS;
  sQ[threadIdx.x] = accQ;
  __syncthreads();
  for (int s = 128; s; s >>= 1) {
    if (threadIdx.x < s) {
      sS[threadIdx.x] += sS[threadIdx.x + s];
      sQ[threadIdx.x] += sQ[threadIdx.x + s];
    }
    __syncthreads();
  }
  if (threadIdx.x == 0) {
    atomicAdd(&red[0], sS[0]);
    atomicAdd(&red[1], sQ[0]);
  }
}

__global__ __launch_bounds__(256) void bn2(const float* __restrict__ z,
                                           const float* __restrict__ red,
                                           const float* __restrict__ gamma,
                                           const float* __restrict__ beta,
                                           float* __restrict__ out) {
  int i = blockIdx.x * 256 + threadIdx.x;
  if (i >= N_NODES) return;
  float mu = red[0] * (1.0f / N_NODES);
  float var = red[1] * (1.0f / N_NODES) - mu * mu;
  out[i] = (z[i] - mu) * rsqrtf(var + BN_EPS) * gamma[0] + beta[0];
}

// ---------------------------------------------------------------------------
extern "C" void kernel_launch(void* const* d_in, const int* in_sizes, int n_in,
                              void* d_out, int out_size, void* d_ws, size_t ws_size,
                              hipStream_t stream) {
  const float* feature = (const float*)d_in[0];
  const int* eidx = (const int*)d_in[1];
  const float* head_W = (const float*)d_in[2];
  const float* head_b = (const float*)d_in[3];
  const float* gin_W1 = (const float*)d_in[4];
  const float* gin_b1 = (const float*)d_in[5];
  const float* lin_W1 = (const float*)d_in[6];
  const float* lin_b1 = (const float*)d_in[7];
  const float* gin_W2 = (const float*)d_in[8];
  const float* gin_b2 = (const float*)d_in[9];
  const float* lin_W2 = (const float*)d_in[10];
  const float* lin_b2 = (const float*)d_in[11];
  const float* tail_W = (const float*)d_in[12];
  const float* tail_b = (const float*)d_in[13];
  const float* bn_gamma = (const float*)d_in[14];
  const float* bn_beta = (const float*)d_in[15];

  float* A = (float*)d_ws;                       // N x 128
  float* B = A + (size_t)N_NODES * DH;           // N x 128
  float* z = B + (size_t)N_NODES * DH;           // N
  float* red = z + N_NODES;                      // 2 floats

  const size_t xbytes = (size_t)N_NODES * DH * sizeof(float);
  const int gemm_grid = (N_NODES + 63) / 64;
  const int scat_grid = (N_EDGES * 32 + 255) / 256;

  hipMemsetAsync(red, 0, 2 * sizeof(float), stream);

  // head: A = relu(feature @ head_W + head_b)
  gemm128<512, true><<<gemm_grid, 256, 0, stream>>>(feature, head_W, head_b, A, N_NODES);

  // layer 1: y = x + segment_sum(x[src] -> dst)   (B = y)
  hipMemcpyAsync(B, A, xbytes, hipMemcpyDeviceToDevice, stream);
  scatter_add<<<scat_grid, 256, 0, stream>>>(A, eidx, B);
  // h = relu(y @ gin_W1 + gin_b1)  -> A
  gemm128<128, true><<<gemm_grid, 256, 0, stream>>>(B, gin_W1, gin_b1, A, N_NODES);
  // x2 = h @ lin_W1 + lin_b1       -> B
  gemm128<128, false><<<gemm_grid, 256, 0, stream>>>(A, lin_W1, lin_b1, B, N_NODES);

  // layer 2 (x = B)
  hipMemcpyAsync(A, B, xbytes, hipMemcpyDeviceToDevice, stream);
  scatter_add<<<scat_grid, 256, 0, stream>>>(B, eidx, A);
  gemm128<128, true><<<gemm_grid, 256, 0, stream>>>(A, gin_W2, gin_b2, B, N_NODES);
  gemm128<128, false><<<gemm_grid, 256, 0, stream>>>(B, lin_W2, lin_b2, A, N_NODES);

  // tail + batchnorm
  tail_bn1<<<256, 256, 0, stream>>>(A, tail_W, tail_b, z, red);
  bn2<<<(N_NODES + 255) / 256, 256, 0, stream>>>(z, red, bn_gamma, bn_beta, (float*)d_out);
}

// Round 2
// 587.049 us; speedup vs baseline: 4.1845x; 4.1845x over previous
//
#include <hip/hip_runtime.h>

#define N_NODES 50000
#define N_EDGES 600000
#define DH 128
#define BN_EPS 1e-5f
#define SCAN_BLOCKS ((N_NODES + 255) / 256)   // 196

// ---------------------------------------------------------------------------
// Register-tiled fp32 GEMM: C[M,128] = act(A[M,K] @ W[K,128] + bias)
// BM=64, BN=128 (full width), BK=32. 256 threads, each computes 4x8 outputs.
// ---------------------------------------------------------------------------
template <int K, bool RELU>
__global__ __launch_bounds__(256) void gemm128(const float* __restrict__ A,
                                               const float* __restrict__ W,
                                               const float* __restrict__ bias,
                                               float* __restrict__ C, int M) {
  constexpr int BM = 64;
  constexpr int BK = 32;
  __shared__ __align__(16) float As[BK][BM + 1];  // transposed, padded
  __shared__ __align__(16) float Bs[BK][DH];

  const int tid = threadIdx.x;
  const int tr = tid >> 4;   // 0..15 -> row group (4 rows each)
  const int tc = tid & 15;   // 0..15 -> col group (8 cols each)
  const int m0 = blockIdx.x * BM;

  float acc[4][8];
#pragma unroll
  for (int i = 0; i < 4; ++i)
#pragma unroll
    for (int j = 0; j < 8; ++j) acc[i][j] = 0.f;

  for (int k0 = 0; k0 < K; k0 += BK) {
#pragma unroll
    for (int l = 0; l < 2; ++l) {
      int id = tid + l * 256;        // 0..511
      int ar = id >> 3;              // 0..63
      int ac = (id & 7) * 4;         // 0..28
      int row = m0 + ar;
      float4 v = make_float4(0.f, 0.f, 0.f, 0.f);
      if (row < M) v = *(const float4*)(A + (size_t)row * K + k0 + ac);
      As[ac + 0][ar] = v.x;
      As[ac + 1][ar] = v.y;
      As[ac + 2][ar] = v.z;
      As[ac + 3][ar] = v.w;
    }
#pragma unroll
    for (int l = 0; l < 4; ++l) {
      int id = tid + l * 256;        // 0..1023
      int wr = id >> 5;              // 0..31
      int wc = (id & 31) * 4;        // 0..124
      *(float4*)&Bs[wr][wc] = *(const float4*)(W + (size_t)(k0 + wr) * DH + wc);
    }
    __syncthreads();

#pragma unroll
    for (int k = 0; k < BK; ++k) {
      float a0 = As[k][tr * 4 + 0];
      float a1 = As[k][tr * 4 + 1];
      float a2 = As[k][tr * 4 + 2];
      float a3 = As[k][tr * 4 + 3];
      float4 b0 = *(const float4*)&Bs[k][tc * 8];
      float4 b1 = *(const float4*)&Bs[k][tc * 8 + 4];
      acc[0][0] += a0 * b0.x; acc[0][1] += a0 * b0.y; acc[0][2] += a0 * b0.z; acc[0][3] += a0 * b0.w;
      acc[0][4] += a0 * b1.x; acc[0][5] += a0 * b1.y; acc[0][6] += a0 * b1.z; acc[0][7] += a0 * b1.w;
      acc[1][0] += a1 * b0.x; acc[1][1] += a1 * b0.y; acc[1][2] += a1 * b0.z; acc[1][3] += a1 * b0.w;
      acc[1][4] += a1 * b1.x; acc[1][5] += a1 * b1.y; acc[1][6] += a1 * b1.z; acc[1][7] += a1 * b1.w;
      acc[2][0] += a2 * b0.x; acc[2][1] += a2 * b0.y; acc[2][2] += a2 * b0.z; acc[2][3] += a2 * b0.w;
      acc[2][4] += a2 * b1.x; acc[2][5] += a2 * b1.y; acc[2][6] += a2 * b1.z; acc[2][7] += a2 * b1.w;
      acc[3][0] += a3 * b0.x; acc[3][1] += a3 * b0.y; acc[3][2] += a3 * b0.z; acc[3][3] += a3 * b0.w;
      acc[3][4] += a3 * b1.x; acc[3][5] += a3 * b1.y; acc[3][6] += a3 * b1.z; acc[3][7] += a3 * b1.w;
    }
    __syncthreads();
  }

  float4 bia0 = *(const float4*)&bias[tc * 8];
  float4 bia1 = *(const float4*)&bias[tc * 8 + 4];
#pragma unroll
  for (int i = 0; i < 4; ++i) {
    int row = m0 + tr * 4 + i;
    if (row >= M) break;
    float4 c0, c1;
    c0.x = acc[i][0] + bia0.x; c0.y = acc[i][1] + bia0.y;
    c0.z = acc[i][2] + bia0.z; c0.w = acc[i][3] + bia0.w;
    c1.x = acc[i][4] + bia1.x; c1.y = acc[i][5] + bia1.y;
    c1.z = acc[i][6] + bia1.z; c1.w = acc[i][7] + bia1.w;
    if (RELU) {
      c0.x = fmaxf(c0.x, 0.f); c0.y = fmaxf(c0.y, 0.f);
      c0.z = fmaxf(c0.z, 0.f); c0.w = fmaxf(c0.w, 0.f);
      c1.x = fmaxf(c1.x, 0.f); c1.y = fmaxf(c1.y, 0.f);
      c1.z = fmaxf(c1.z, 0.f); c1.w = fmaxf(c1.w, 0.f);
    }
    float* cp = C + (size_t)row * DH + tc * 8;
    *(float4*)cp = c0;
    *(float4*)(cp + 4) = c1;
  }
}

// ---------------------------------------------------------------------------
// CSR build: degree histogram -> exclusive scan (3 kernels) -> cursor fill.
// ---------------------------------------------------------------------------
__global__ __launch_bounds__(256) void count_deg(const int* __restrict__ eidx,
                                                 int* __restrict__ cnt) {
  int e = blockIdx.x * 256 + threadIdx.x;
  if (e < N_EDGES) atomicAdd(&cnt[eidx[N_EDGES + e]], 1);
}

__global__ __launch_bounds__(256) void scan_block(const int* __restrict__ cnt,
                                                  int* __restrict__ rs,
                                                  int* __restrict__ partials) {
  int t = threadIdx.x;
  int i = blockIdx.x * 256 + t;
  int v = (i < N_NODES) ? cnt[i] : 0;
  __shared__ int s[256];
  s[t] = v;
  __syncthreads();
#pragma unroll
  for (int off = 1; off < 256; off <<= 1) {
    int add = (t >= off) ? s[t - off] : 0;
    __syncthreads();
    s[t] += add;
    __syncthreads();
  }
  if (i < N_NODES) rs[i] = s[t] - v;        // block-local exclusive
  if (t == 255) partials[blockIdx.x] = s[255];
}

__global__ __launch_bounds__(256) void scan_partials(int* __restrict__ partials) {
  int t = threadIdx.x;
  int v = (t < SCAN_BLOCKS) ? partials[t] : 0;
  __shared__ int s[256];
  s[t] = v;
  __syncthreads();
#pragma unroll
  for (int off = 1; off < 256; off <<= 1) {
    int add = (t >= off) ? s[t - off] : 0;
    __syncthreads();
    s[t] += add;
    __syncthreads();
  }
  if (t < SCAN_BLOCKS) partials[t] = s[t] - v;  // exclusive
}

__global__ __launch_bounds__(256) void add_offsets(int* __restrict__ rs,
                                                   const int* __restrict__ partials) {
  int i = blockIdx.x * 256 + threadIdx.x;
  if (i < N_NODES) rs[i] += partials[blockIdx.x];
  if (i == 0) rs[N_NODES] = N_EDGES;
}

__global__ __launch_bounds__(256) void fill_csr(const int* __restrict__ eidx,
                                                const int* __restrict__ rs,
                                                int* __restrict__ cursor,
                                                int* __restrict__ esrc) {
  int e = blockIdx.x * 256 + threadIdx.x;
  if (e >= N_EDGES) return;
  int d = eidx[N_EDGES + e];
  int p = atomicAdd(&cursor[d], 1);
  esrc[rs[d] + p] = eidx[e];
}

// ---------------------------------------------------------------------------
// Aggregation gather: y[i] = x[i] + sum_{j in in(i)} x[src_j].
// One 64-lane wave per node; each lane holds a float2 slice of the row.
// ---------------------------------------------------------------------------
__global__ __launch_bounds__(256) void gin_aggregate(const float* __restrict__ x,
                                                     const int* __restrict__ rs,
                                                     const int* __restrict__ esrc,
                                                     float* __restrict__ y) {
  int node = blockIdx.x * 4 + (threadIdx.x >> 6);
  int lane = threadIdx.x & 63;
  if (node >= N_NODES) return;
  const float2* x2 = (const float2*)x;
  float2 acc = x2[(size_t)node * 64 + lane];  // self term (y = x + agg)
  int beg = rs[node];
  int end = rs[node + 1];
  int j = beg;
  for (; j + 4 <= end; j += 4) {
    int s0 = esrc[j + 0];
    int s1 = esrc[j + 1];
    int s2 = esrc[j + 2];
    int s3 = esrc[j + 3];
    float2 v0 = x2[(size_t)s0 * 64 + lane];
    float2 v1 = x2[(size_t)s1 * 64 + lane];
    float2 v2 = x2[(size_t)s2 * 64 + lane];
    float2 v3 = x2[(size_t)s3 * 64 + lane];
    acc.x += (v0.x + v1.x) + (v2.x + v3.x);
    acc.y += (v0.y + v1.y) + (v2.y + v3.y);
  }
  for (; j < end; ++j) {
    int s = esrc[j];
    float2 v = x2[(size_t)s * 64 + lane];
    acc.x += v.x;
    acc.y += v.y;
  }
  ((float2*)y)[(size_t)node * 64 + lane] = acc;
}

// ---------------------------------------------------------------------------
// Tail: z[i] = dot(x[i,:], tail_W) + tail_b, plus BN batch-stat partials.
// ---------------------------------------------------------------------------
__global__ __launch_bounds__(256) void tail_bn1(const float* __restrict__ x,
                                                const float* __restrict__ tw,
                                                const float* __restrict__ tb,
                                                float* __restrict__ z,
                                                float* __restrict__ red) {
  const int lane = threadIdx.x & 31;
  const int grp = threadIdx.x >> 5;  // 0..7
  float4 w = *(const float4*)(tw + lane * 4);
  float accS = 0.f, accQ = 0.f;
  for (int node = blockIdx.x * 8 + grp; node < N_NODES; node += gridDim.x * 8) {
    float4 v = *(const float4*)(x + (size_t)node * DH + lane * 4);
    float p = v.x * w.x + v.y * w.y + v.z * w.z + v.w * w.w;
#pragma unroll
    for (int m = 16; m; m >>= 1) p += __shfl_xor(p, m, 32);
    if (lane == 0) {
      float zv = p + tb[0];
      z[node] = zv;
      accS += zv;
      accQ += zv * zv;
    }
  }
  __shared__ float sS[256];
  __shared__ float sQ[256];
  sS[threadIdx.x] = accS;
  sQ[threadIdx.x] = accQ;
  __syncthreads();
  for (int s = 128; s; s >>= 1) {
    if (threadIdx.x < s) {
      sS[threadIdx.x] += sS[threadIdx.x + s];
      sQ[threadIdx.x] += sQ[threadIdx.x + s];
    }
    __syncthreads();
  }
  if (threadIdx.x == 0) {
    atomicAdd(&red[0], sS[0]);
    atomicAdd(&red[1], sQ[0]);
  }
}

__global__ __launch_bounds__(256) void bn2(const float* __restrict__ z,
                                           const float* __restrict__ red,
                                           const float* __restrict__ gamma,
                                           const float* __restrict__ beta,
                                           float* __restrict__ out) {
  int i = blockIdx.x * 256 + threadIdx.x;
  if (i >= N_NODES) return;
  float mu = red[0] * (1.0f / N_NODES);
  float var = red[1] * (1.0f / N_NODES) - mu * mu;
  out[i] = (z[i] - mu) * rsqrtf(var + BN_EPS) * gamma[0] + beta[0];
}

// ---------------------------------------------------------------------------
extern "C" void kernel_launch(void* const* d_in, const int* in_sizes, int n_in,
                              void* d_out, int out_size, void* d_ws, size_t ws_size,
                              hipStream_t stream) {
  const float* feature = (const float*)d_in[0];
  const int* eidx = (const int*)d_in[1];
  const float* head_W = (const float*)d_in[2];
  const float* head_b = (const float*)d_in[3];
  const float* gin_W1 = (const float*)d_in[4];
  const float* gin_b1 = (const float*)d_in[5];
  const float* lin_W1 = (const float*)d_in[6];
  const float* lin_b1 = (const float*)d_in[7];
  const float* gin_W2 = (const float*)d_in[8];
  const float* gin_b2 = (const float*)d_in[9];
  const float* lin_W2 = (const float*)d_in[10];
  const float* lin_b2 = (const float*)d_in[11];
  const float* tail_W = (const float*)d_in[12];
  const float* tail_b = (const float*)d_in[13];
  const float* bn_gamma = (const float*)d_in[14];
  const float* bn_beta = (const float*)d_in[15];

  float* A = (float*)d_ws;                       // N x 128
  float* B = A + (size_t)N_NODES * DH;           // N x 128
  float* z = B + (size_t)N_NODES * DH;           // N
  float* red = z + N_NODES;                      // 2 floats
  int* row_start = (int*)(red + 2);              // N+1
  int* cnt = row_start + (N_NODES + 1);          // N (histogram, then cursor)
  int* partials = cnt + N_NODES;                 // SCAN_BLOCKS (256 for align)
  int* esrc = partials + 256;                    // E

  const int gemm_grid = (N_NODES + 63) / 64;
  const int edge_grid = (N_EDGES + 255) / 256;
  const int agg_grid = (N_NODES + 3) / 4;

  // ---- CSR build (once; reused by both GIN layers) ----
  hipMemsetAsync(cnt, 0, N_NODES * sizeof(int), stream);
  hipMemsetAsync(red, 0, 2 * sizeof(float), stream);
  count_deg<<<edge_grid, 256, 0, stream>>>(eidx, cnt);
  scan_block<<<SCAN_BLOCKS, 256, 0, stream>>>(cnt, row_start, partials);
  scan_partials<<<1, 256, 0, stream>>>(partials);
  add_offsets<<<SCAN_BLOCKS, 256, 0, stream>>>(row_start, partials);
  hipMemsetAsync(cnt, 0, N_NODES * sizeof(int), stream);  // reuse as cursor
  fill_csr<<<edge_grid, 256, 0, stream>>>(eidx, row_start, cnt, esrc);

  // ---- head: A = relu(feature @ head_W + head_b) ----
  gemm128<512, true><<<gemm_grid, 256, 0, stream>>>(feature, head_W, head_b, A, N_NODES);

  // ---- layer 1 ----
  gin_aggregate<<<agg_grid, 256, 0, stream>>>(A, row_start, esrc, B);  // B = A + agg(A)
  gemm128<128, true><<<gemm_grid, 256, 0, stream>>>(B, gin_W1, gin_b1, A, N_NODES);
  gemm128<128, false><<<gemm_grid, 256, 0, stream>>>(A, lin_W1, lin_b1, B, N_NODES);

  // ---- layer 2 ----
  gin_aggregate<<<agg_grid, 256, 0, stream>>>(B, row_start, esrc, A);  // A = B + agg(B)
  gemm128<128, true><<<gemm_grid, 256, 0, stream>>>(A, gin_W2, gin_b2, B, N_NODES);
  gemm128<128, false><<<gemm_grid, 256, 0, stream>>>(B, lin_W2, lin_b2, A, N_NODES);

  // ---- tail + batchnorm ----
  tail_bn1<<<256, 256, 0, stream>>>(A, tail_W, tail_b, z, red);
  bn2<<<(N_NODES + 255) / 256, 256, 0, stream>>>(z, red, bn_gamma, bn_beta, (float*)d_out);
}

// Round 3
// 487.709 us; speedup vs baseline: 5.0368x; 1.2037x over previous
//
#include <hip/hip_runtime.h>

#define N_NODES 50000
#define N_EDGES 600000
#define DH 128
#define BN_EPS 1e-5f
#define SCAN_BLOCKS ((N_NODES + 255) / 256)   // 196

typedef __attribute__((ext_vector_type(8))) short bf16x8;
typedef __attribute__((ext_vector_type(4))) float f32x4;

// round-to-nearest-even fp32 -> bf16 (bit trick, sign-safe)
__device__ inline unsigned short f2bf(float x) {
  unsigned u = __float_as_uint(x);
  return (unsigned short)((u + 0x7FFFu + ((u >> 16) & 1u)) >> 16);
}
__device__ inline float bf2f(unsigned short h) {
  return __uint_as_float(((unsigned)h) << 16);
}

// ---------------------------------------------------------------------------
// Pre-split W[K][128] into bf16 hi/lo planes laid out in MFMA B-fragment
// order: plane[((kstep*8 + ctile)*64 + lane)*8 + j]
//   where k = kstep*32 + (lane>>4)*8 + j, n = ctile*16 + (lane&15).
// ---------------------------------------------------------------------------
__global__ __launch_bounds__(256) void convert_W(const float* __restrict__ W,
                                                 unsigned short* __restrict__ hi,
                                                 unsigned short* __restrict__ lo,
                                                 int K) {
  int idx = blockIdx.x * 256 + threadIdx.x;
  if (idx >= K * 128) return;
  int k = idx >> 7;
  int n = idx & 127;
  float x = W[idx];
  unsigned short h = f2bf(x);
  unsigned short l = f2bf(x - bf2f(h));
  int kstep = k >> 5;
  int ctile = n >> 4;
  int lane = ((k >> 3) & 3) * 16 + (n & 15);
  int j = k & 7;
  size_t off = ((size_t)(kstep * 8 + ctile) * 64 + lane) * 8 + j;
  hi[off] = h;
  lo[off] = l;
}

// ---------------------------------------------------------------------------
// Split-bf16 MFMA GEMM: C[M,128] = act(A[M,K] @ W + bias), fp32-equivalent
// precision via A*B ~= Ah*Bh + Ah*Bl + Al*Bh  (drops Al*Bl ~ 2^-18 rel).
// Block: 256 thr = 4 waves; BM=128 (32 rows/wave), BN=128 (8 col-tiles).
// A staged fp32->hi/lo in LDS (stride 40 u16 -> 2-way bank alias, free).
// B copied from pre-split fragment-ordered planes (flat float4 copy).
// ---------------------------------------------------------------------------
template <int K, bool RELU>
__global__ __launch_bounds__(256) void gemm_mfma(const float* __restrict__ A,
                                                 const unsigned short* __restrict__ Bh,
                                                 const unsigned short* __restrict__ Bl,
                                                 const float* __restrict__ bias,
                                                 float* __restrict__ C, int M) {
  constexpr int KSTEPS = K / 32;
  constexpr int ASTR = 40;  // padded row stride (u16) for A planes
  __shared__ unsigned short Ah[128 * ASTR];
  __shared__ unsigned short Al[128 * ASTR];
  __shared__ unsigned short Bhs[8 * 64 * 8];
  __shared__ unsigned short Bls[8 * 64 * 8];

  const int tid = threadIdx.x;
  const int wave = tid >> 6;
  const int lane = tid & 63;
  const int m0 = blockIdx.x * 128;

  // A-staging mapping: each thread owns row tid>>1, half-row tid&1 (16 k's)
  const int s_row = tid >> 1;
  const int s_half = tid & 1;
  const bool s_ok = (m0 + s_row) < M;
  const float* srcA = A + (size_t)(m0 + s_row) * K + s_half * 16;

  f32x4 acc[2][8];
#pragma unroll
  for (int r = 0; r < 2; ++r)
#pragma unroll
    for (int c = 0; c < 8; ++c) acc[r][c] = (f32x4){0.f, 0.f, 0.f, 0.f};

  for (int ks = 0; ks < KSTEPS; ++ks) {
    // ---- stage A tile (128 x 32 fp32 -> bf16 hi/lo) ----
#pragma unroll
    for (int c = 0; c < 4; ++c) {
      float4 v = make_float4(0.f, 0.f, 0.f, 0.f);
      if (s_ok) v = *(const float4*)(srcA + ks * 32 + c * 4);
      ushort4 h4, l4;
      h4.x = f2bf(v.x); l4.x = f2bf(v.x - bf2f(h4.x));
      h4.y = f2bf(v.y); l4.y = f2bf(v.y - bf2f(h4.y));
      h4.z = f2bf(v.z); l4.z = f2bf(v.z - bf2f(h4.z));
      h4.w = f2bf(v.w); l4.w = f2bf(v.w - bf2f(h4.w));
      int base = s_row * ASTR + s_half * 16 + c * 4;
      *(ushort4*)&Ah[base] = h4;
      *(ushort4*)&Al[base] = l4;
    }
    // ---- stage B planes (8 KB each, already fragment-ordered) ----
    {
      const float4* sh = (const float4*)(Bh + (size_t)ks * 4096);
      const float4* sl = (const float4*)(Bl + (size_t)ks * 4096);
      float4* dh = (float4*)Bhs;
      float4* dl = (float4*)Bls;
#pragma unroll
      for (int i = 0; i < 2; ++i) {
        dh[tid * 2 + i] = sh[tid * 2 + i];
        dl[tid * 2 + i] = sl[tid * 2 + i];
      }
    }
    __syncthreads();

    // ---- fragments + MFMA ----
    bf16x8 afh[2], afl[2];
#pragma unroll
    for (int r = 0; r < 2; ++r) {
      int arow = wave * 32 + r * 16 + (lane & 15);
      int aoff = arow * ASTR + (lane >> 4) * 8;
      afh[r] = *(const bf16x8*)&Ah[aoff];
      afl[r] = *(const bf16x8*)&Al[aoff];
    }
#pragma unroll
    for (int c = 0; c < 8; ++c) {
      bf16x8 bh = *(const bf16x8*)&Bhs[(c * 64 + lane) * 8];
      bf16x8 bl = *(const bf16x8*)&Bls[(c * 64 + lane) * 8];
#pragma unroll
      for (int r = 0; r < 2; ++r) {
        acc[r][c] = __builtin_amdgcn_mfma_f32_16x16x32_bf16(afh[r], bh, acc[r][c], 0, 0, 0);
        acc[r][c] = __builtin_amdgcn_mfma_f32_16x16x32_bf16(afh[r], bl, acc[r][c], 0, 0, 0);
        acc[r][c] = __builtin_amdgcn_mfma_f32_16x16x32_bf16(afl[r], bh, acc[r][c], 0, 0, 0);
      }
    }
    __syncthreads();
  }

  // ---- epilogue: C/D layout col=lane&15, row=(lane>>4)*4+reg ----
  const int coln = lane & 15;
  const int rown = (lane >> 4) * 4;
#pragma unroll
  for (int c = 0; c < 8; ++c) {
    float bv = bias[c * 16 + coln];
#pragma unroll
    for (int r = 0; r < 2; ++r) {
#pragma unroll
      for (int reg = 0; reg < 4; ++reg) {
        int row = m0 + wave * 32 + r * 16 + rown + reg;
        if (row < M) {
          float v = acc[r][c][reg] + bv;
          if (RELU) v = fmaxf(v, 0.f);
          C[(size_t)row * DH + c * 16 + coln] = v;
        }
      }
    }
  }
}

// ---------------------------------------------------------------------------
// CSR build: degree histogram -> exclusive scan (3 kernels) -> cursor fill.
// ---------------------------------------------------------------------------
__global__ __launch_bounds__(256) void count_deg(const int* __restrict__ eidx,
                                                 int* __restrict__ cnt) {
  int e = blockIdx.x * 256 + threadIdx.x;
  if (e < N_EDGES) atomicAdd(&cnt[eidx[N_EDGES + e]], 1);
}

__global__ __launch_bounds__(256) void scan_block(const int* __restrict__ cnt,
                                                  int* __restrict__ rs,
                                                  int* __restrict__ partials) {
  int t = threadIdx.x;
  int i = blockIdx.x * 256 + t;
  int v = (i < N_NODES) ? cnt[i] : 0;
  __shared__ int s[256];
  s[t] = v;
  __syncthreads();
#pragma unroll
  for (int off = 1; off < 256; off <<= 1) {
    int add = (t >= off) ? s[t - off] : 0;
    __syncthreads();
    s[t] += add;
    __syncthreads();
  }
  if (i < N_NODES) rs[i] = s[t] - v;
  if (t == 255) partials[blockIdx.x] = s[255];
}

__global__ __launch_bounds__(256) void scan_partials(int* __restrict__ partials) {
  int t = threadIdx.x;
  int v = (t < SCAN_BLOCKS) ? partials[t] : 0;
  __shared__ int s[256];
  s[t] = v;
  __syncthreads();
#pragma unroll
  for (int off = 1; off < 256; off <<= 1) {
    int add = (t >= off) ? s[t - off] : 0;
    __syncthreads();
    s[t] += add;
    __syncthreads();
  }
  if (t < SCAN_BLOCKS) partials[t] = s[t] - v;
}

__global__ __launch_bounds__(256) void add_offsets(int* __restrict__ rs,
                                                   const int* __restrict__ partials) {
  int i = blockIdx.x * 256 + threadIdx.x;
  if (i < N_NODES) rs[i] += partials[blockIdx.x];
  if (i == 0) rs[N_NODES] = N_EDGES;
}

__global__ __launch_bounds__(256) void fill_csr(const int* __restrict__ eidx,
                                                const int* __restrict__ rs,
                                                int* __restrict__ cursor,
                                                int* __restrict__ esrc) {
  int e = blockIdx.x * 256 + threadIdx.x;
  if (e >= N_EDGES) return;
  int d = eidx[N_EDGES + e];
  int p = atomicAdd(&cursor[d], 1);
  esrc[rs[d] + p] = eidx[e];
}

// ---------------------------------------------------------------------------
// Aggregation gather: y[i] = x[i] + sum_{j in in(i)} x[src_j].
// ---------------------------------------------------------------------------
__global__ __launch_bounds__(256) void gin_aggregate(const float* __restrict__ x,
                                                     const int* __restrict__ rs,
                                                     const int* __restrict__ esrc,
                                                     float* __restrict__ y) {
  int node = blockIdx.x * 4 + (threadIdx.x >> 6);
  int lane = threadIdx.x & 63;
  if (node >= N_NODES) return;
  const float2* x2 = (const float2*)x;
  float2 acc = x2[(size_t)node * 64 + lane];
  int beg = rs[node];
  int end = rs[node + 1];
  int j = beg;
  for (; j + 4 <= end; j += 4) {
    int s0 = esrc[j + 0];
    int s1 = esrc[j + 1];
    int s2 = esrc[j + 2];
    int s3 = esrc[j + 3];
    float2 v0 = x2[(size_t)s0 * 64 + lane];
    float2 v1 = x2[(size_t)s1 * 64 + lane];
    float2 v2 = x2[(size_t)s2 * 64 + lane];
    float2 v3 = x2[(size_t)s3 * 64 + lane];
    acc.x += (v0.x + v1.x) + (v2.x + v3.x);
    acc.y += (v0.y + v1.y) + (v2.y + v3.y);
  }
  for (; j < end; ++j) {
    int s = esrc[j];
    float2 v = x2[(size_t)s * 64 + lane];
    acc.x += v.x;
    acc.y += v.y;
  }
  ((float2*)y)[(size_t)node * 64 + lane] = acc;
}

// ---------------------------------------------------------------------------
// Tail: z[i] = dot(x[i,:], tail_W) + tail_b, plus BN batch-stat partials.
// ---------------------------------------------------------------------------
__global__ __launch_bounds__(256) void tail_bn1(const float* __restrict__ x,
                                                const float* __restrict__ tw,
                                                const float* __restrict__ tb,
                                                float* __restrict__ z,
                                                float* __restrict__ red) {
  const int lane = threadIdx.x & 31;
  const int grp = threadIdx.x >> 5;
  float4 w = *(const float4*)(tw + lane * 4);
  float accS = 0.f, accQ = 0.f;
  for (int node = blockIdx.x * 8 + grp; node < N_NODES; node += gridDim.x * 8) {
    float4 v = *(const float4*)(x + (size_t)node * DH + lane * 4);
    float p = v.x * w.x + v.y * w.y + v.z * w.z + v.w * w.w;
#pragma unroll
    for (int m = 16; m; m >>= 1) p += __shfl_xor(p, m, 32);
    if (lane == 0) {
      float zv = p + tb[0];
      z[node] = zv;
      accS += zv;
      accQ += zv * zv;
    }
  }
  __shared__ float sS[256];
  __shared__ float sQ[256];
  sS[threadIdx.x] = accS;
  sQ[threadIdx.x] = accQ;
  __syncthreads();
  for (int s = 128; s; s >>= 1) {
    if (threadIdx.x < s) {
      sS[threadIdx.x] += sS[threadIdx.x + s];
      sQ[threadIdx.x] += sQ[threadIdx.x + s];
    }
    __syncthreads();
  }
  if (threadIdx.x == 0) {
    atomicAdd(&red[0], sS[0]);
    atomicAdd(&red[1], sQ[0]);
  }
}

__global__ __launch_bounds__(256) void bn2(const float* __restrict__ z,
                                           const float* __restrict__ red,
                                           const float* __restrict__ gamma,
                                           const float* __restrict__ beta,
                                           float* __restrict__ out) {
  int i = blockIdx.x * 256 + threadIdx.x;
  if (i >= N_NODES) return;
  float mu = red[0] * (1.0f / N_NODES);
  float var = red[1] * (1.0f / N_NODES) - mu * mu;
  out[i] = (z[i] - mu) * rsqrtf(var + BN_EPS) * gamma[0] + beta[0];
}

// ---------------------------------------------------------------------------
extern "C" void kernel_launch(void* const* d_in, const int* in_sizes, int n_in,
                              void* d_out, int out_size, void* d_ws, size_t ws_size,
                              hipStream_t stream) {
  const float* feature = (const float*)d_in[0];
  const int* eidx = (const int*)d_in[1];
  const float* head_W = (const float*)d_in[2];
  const float* head_b = (const float*)d_in[3];
  const float* gin_W1 = (const float*)d_in[4];
  const float* gin_b1 = (const float*)d_in[5];
  const float* lin_W1 = (const float*)d_in[6];
  const float* lin_b1 = (const float*)d_in[7];
  const float* gin_W2 = (const float*)d_in[8];
  const float* gin_b2 = (const float*)d_in[9];
  const float* lin_W2 = (const float*)d_in[10];
  const float* lin_b2 = (const float*)d_in[11];
  const float* tail_W = (const float*)d_in[12];
  const float* tail_b = (const float*)d_in[13];
  const float* bn_gamma = (const float*)d_in[14];
  const float* bn_beta = (const float*)d_in[15];

  float* A = (float*)d_ws;                       // N x 128
  float* B = A + (size_t)N_NODES * DH;           // N x 128
  float* z = B + (size_t)N_NODES * DH;           // N
  float* red = z + N_NODES;                      // 2 floats
  int* row_start = (int*)(red + 2);              // N+1
  int* cnt = row_start + (N_NODES + 1);          // N
  int* partials = cnt + N_NODES;                 // 256
  int* esrc = partials + 256;                    // E
  unsigned short* wp =
      (unsigned short*)(((uintptr_t)(esrc + N_EDGES) + 15) & ~(uintptr_t)15);
  unsigned short* hH = wp;            // head hi: 512*128
  unsigned short* hL = hH + 65536;    // head lo
  unsigned short* g1H = hL + 65536;   // 128*128 each below
  unsigned short* g1L = g1H + 16384;
  unsigned short* l1H = g1L + 16384;
  unsigned short* l1L = l1H + 16384;
  unsigned short* g2H = l1L + 16384;
  unsigned short* g2L = g2H + 16384;
  unsigned short* l2H = g2L + 16384;
  unsigned short* l2L = l2H + 16384;

  const int gemm_grid = (N_NODES + 127) / 128;   // 391
  const int edge_grid = (N_EDGES + 255) / 256;
  const int agg_grid = (N_NODES + 3) / 4;

  // ---- weight pre-split (tiny) ----
  convert_W<<<(512 * 128 + 255) / 256, 256, 0, stream>>>(head_W, hH, hL, 512);
  convert_W<<<64, 256, 0, stream>>>(gin_W1, g1H, g1L, 128);
  convert_W<<<64, 256, 0, stream>>>(lin_W1, l1H, l1L, 128);
  convert_W<<<64, 256, 0, stream>>>(gin_W2, g2H, g2L, 128);
  convert_W<<<64, 256, 0, stream>>>(lin_W2, l2H, l2L, 128);

  // ---- CSR build (once; reused by both GIN layers) ----
  hipMemsetAsync(cnt, 0, N_NODES * sizeof(int), stream);
  hipMemsetAsync(red, 0, 2 * sizeof(float), stream);
  count_deg<<<edge_grid, 256, 0, stream>>>(eidx, cnt);
  scan_block<<<SCAN_BLOCKS, 256, 0, stream>>>(cnt, row_start, partials);
  scan_partials<<<1, 256, 0, stream>>>(partials);
  add_offsets<<<SCAN_BLOCKS, 256, 0, stream>>>(row_start, partials);
  hipMemsetAsync(cnt, 0, N_NODES * sizeof(int), stream);
  fill_csr<<<edge_grid, 256, 0, stream>>>(eidx, row_start, cnt, esrc);

  // ---- head: A = relu(feature @ head_W + head_b) ----
  gemm_mfma<512, true><<<gemm_grid, 256, 0, stream>>>(feature, hH, hL, head_b, A, N_NODES);

  // ---- layer 1 ----
  gin_aggregate<<<agg_grid, 256, 0, stream>>>(A, row_start, esrc, B);
  gemm_mfma<128, true><<<gemm_grid, 256, 0, stream>>>(B, g1H, g1L, gin_b1, A, N_NODES);
  gemm_mfma<128, false><<<gemm_grid, 256, 0, stream>>>(A, l1H, l1L, lin_b1, B, N_NODES);

  // ---- layer 2 ----
  gin_aggregate<<<agg_grid, 256, 0, stream>>>(B, row_start, esrc, A);
  gemm_mfma<128, true><<<gemm_grid, 256, 0, stream>>>(A, g2H, g2L, gin_b2, B, N_NODES);
  gemm_mfma<128, false><<<gemm_grid, 256, 0, stream>>>(B, l2H, l2L, lin_b2, A, N_NODES);

  // ---- tail + batchnorm ----
  tail_bn1<<<256, 256, 0, stream>>>(A, tail_W, tail_b, z, red);
  bn2<<<(N_NODES + 255) / 256, 256, 0, stream>>>(z, red, bn_gamma, bn_beta, (float*)d_out);
}